// Round 3
// baseline (341.235 us; speedup 1.0000x reference)
//
#include <hip/hip_runtime.h>

#define T_DIM 8192
#define D_DIM 1024
#define H_DIM 2048
#define N_DIM 4096
#define CHUNK 32
#define LOG2_CHUNK 5
#define NCH   (T_DIM / CHUNK)   // 256

typedef __attribute__((ext_vector_type(8))) short bf16x8;
typedef __attribute__((ext_vector_type(4))) float f32x4;

// ---------------- helpers ----------------

__device__ __forceinline__ unsigned short f2bf(float f) {
    unsigned int u = __float_as_uint(f);
    unsigned int r = (u + 0x7fffu + ((u >> 16) & 1u)) >> 16;  // RNE
    return (unsigned short)r;
}

__device__ __forceinline__ float bf2f(unsigned short u) {
    return __uint_as_float((unsigned int)u << 16);
}

__device__ __forceinline__ void gl_lds16(const unsigned short* g, unsigned short* l) {
    __builtin_amdgcn_global_load_lds(
        (__attribute__((address_space(1))) void*)(g),
        (__attribute__((address_space(3))) void*)(l), 16, 0, 0);
}

// complex rotate-accumulate for one channel
#define CSTEP(A, Bq, H1, H2, V1, V2)                  \
    {                                                 \
        float n1 = (A) * (H1) - (Bq) * (H2) + (V1);   \
        float n2 = (A) * (H2) + (Bq) * (H1) + (V2);   \
        (H1) = n1; (H2) = n2;                         \
    }

// ---------------- kernel 1: per-channel params ----------------

__global__ void params_kernel(const float* __restrict__ lamda,
                              const float* __restrict__ theta,
                              float* __restrict__ pa, float* __restrict__ pb,
                              float* __restrict__ pg) {
    int h = blockIdx.x * 256 + threadIdx.x;
    if (h >= H_DIM) return;
    float y = expf(-expf(lamda[h]));
    float z = expf(theta[h]);
    pg[h] = sqrtf(1.0f - y * y);
    pa[h] = y * cosf(z);
    pb[h] = y * sinf(z);
}

// ---------------- kernel 2: fused fp32 -> bf16 convert (x, B1, B2) ----------------

__global__ void cvt3_kernel(const float4* __restrict__ s0, ushort4* __restrict__ d0, int n0,
                            const float4* __restrict__ s1, ushort4* __restrict__ d1, int n1,
                            const float4* __restrict__ s2, ushort4* __restrict__ d2, int n2) {
    int i = blockIdx.x * 256 + threadIdx.x;
    const float4* s; ushort4* d; int j;
    if (i < n0)                { s = s0; d = d0; j = i; }
    else if (i < n0 + n1)      { s = s1; d = d1; j = i - n0; }
    else if (i < n0 + n1 + n2) { s = s2; d = d2; j = i - n0 - n1; }
    else return;
    float4 f = s[j];
    ushort4 o;
    o.x = f2bf(f.x); o.y = f2bf(f.y); o.z = f2bf(f.z); o.w = f2bf(f.w);
    d[j] = o;
}

// ---------------- kernel 3: bf16 GEMM (A[M,K] x B[N,K]^T), gamma epilogue ----------------
// 128x128 tile, BK=32, 256 threads = 4 waves (2x2), each wave 64x64 via 4x4 MFMA 16x16x32.
// Global-side XOR swizzle of the k-group breaks LDS bank conflicts (verified R2: 8.4M -> 0).

template <bool BF16OUT>
__global__ __launch_bounds__(256) void gemm_bt(
    const unsigned short* __restrict__ A,   // [8192,1024] bf16
    const unsigned short* __restrict__ B,   // [4096,1024] bf16
    const float* __restrict__ gamma,        // [2048]
    void* __restrict__ Cv)                  // [8192,4096] fp32 or bf16
{
    __shared__ unsigned short sA[128 * 32];  // 8 KB
    __shared__ unsigned short sB[128 * 32];  // 8 KB

    const int tid  = threadIdx.x;
    const int lane = tid & 63;
    const int wave = tid >> 6;
    const int quad = lane >> 4;
    const int m16  = lane & 15;
    const int wm = (wave >> 1) << 6;   // 0 or 64
    const int wn = (wave & 1) << 6;

    const int rowA0 = blockIdx.x * 128;
    const int rowB0 = blockIdx.y * 128;

    const int e0 = tid * 8;
    const int r0 = e0 >> 5;            // row in tile (BK=32)
    const int gs = (e0 >> 3) & 3;
    const int k0 = (gs ^ ((r0 >> 1) & 3)) * 8;   // swizzled global k offset
    const int r1 = r0 + 64;

    const unsigned short* a0 = A + (size_t)(rowA0 + r0) * D_DIM + k0;
    const unsigned short* a1 = A + (size_t)(rowA0 + r1) * D_DIM + k0;
    const unsigned short* b0 = B + (size_t)(rowB0 + r0) * D_DIM + k0;
    const unsigned short* b1 = B + (size_t)(rowB0 + r1) * D_DIM + k0;
    unsigned short* la0 = &sA[e0];
    unsigned short* la1 = &sA[e0 + 2048];
    unsigned short* lb0 = &sB[e0];
    unsigned short* lb1 = &sB[e0 + 2048];

    const int grp8 = (quad ^ ((m16 >> 1) & 3)) * 8;

    f32x4 acc[4][4];
#pragma unroll
    for (int i = 0; i < 4; i++)
#pragma unroll
        for (int j = 0; j < 4; j++) acc[i][j] = (f32x4)(0.0f);

    for (int kt = 0; kt < D_DIM; kt += 32) {
        __syncthreads();
        gl_lds16(a0 + kt, la0);
        gl_lds16(a1 + kt, la1);
        gl_lds16(b0 + kt, lb0);
        gl_lds16(b1 + kt, lb1);
        __syncthreads();

        bf16x8 af[4], bfr[4];
#pragma unroll
        for (int i = 0; i < 4; i++)
            af[i] = *(const bf16x8*)&sA[(wm + i * 16 + m16) * 32 + grp8];
#pragma unroll
        for (int i = 0; i < 4; i++)
            bfr[i] = *(const bf16x8*)&sB[(wn + i * 16 + m16) * 32 + grp8];

#pragma unroll
        for (int mi = 0; mi < 4; mi++)
#pragma unroll
            for (int ni = 0; ni < 4; ni++)
                acc[mi][ni] = __builtin_amdgcn_mfma_f32_16x16x32_bf16(
                    af[mi], bfr[ni], acc[mi][ni], 0, 0, 0);
    }

    // epilogue: C/D layout col=lane&15, row=quad*4+reg
    float* Cf = (float*)Cv;
    unsigned short* Cb = (unsigned short*)Cv;
#pragma unroll
    for (int ni = 0; ni < 4; ni++) {
        const int col = rowB0 + wn + ni * 16 + m16;
        const float g = gamma[col & (H_DIM - 1)];
#pragma unroll
        for (int mi = 0; mi < 4; mi++) {
            const int row0 = rowA0 + wm + mi * 16 + quad * 4;
#pragma unroll
            for (int r = 0; r < 4; r++) {
                float val = acc[mi][ni][r] * g;
                if (BF16OUT)
                    Cb[(size_t)(row0 + r) * N_DIM + col] = f2bf(val);
                else
                    Cf[(size_t)(row0 + r) * N_DIM + col] = val;
            }
        }
    }
}

// ---------------- kernel 4a: chunk-local end states, 4 channels/thread ----------------

template <bool BF16IN>
__global__ void scanA(const void* __restrict__ v,        // [T, 4096] bf16 or fp32
                      const float* __restrict__ pa, const float* __restrict__ pb,
                      float* __restrict__ E)             // [NCH][2][H]
{
    int h4 = (blockIdx.x * 256 + threadIdx.x) * 4;   // 0..2044
    int c = blockIdx.y;
    float4 a = *(const float4*)(pa + h4);
    float4 b = *(const float4*)(pb + h4);
    float4 h1 = make_float4(0.f, 0.f, 0.f, 0.f);
    float4 h2 = make_float4(0.f, 0.f, 0.f, 0.f);
    const unsigned short* pb16 = (const unsigned short*)v + (size_t)c * CHUNK * N_DIM + h4;
    const float* pf = (const float*)v + (size_t)c * CHUNK * N_DIM + h4;
#pragma unroll 8
    for (int t = 0; t < CHUNK; t++) {
        float4 v1, v2;
        if (BF16IN) {
            ushort4 u1 = *(const ushort4*)(pb16);
            ushort4 u2 = *(const ushort4*)(pb16 + H_DIM);
            v1 = make_float4(bf2f(u1.x), bf2f(u1.y), bf2f(u1.z), bf2f(u1.w));
            v2 = make_float4(bf2f(u2.x), bf2f(u2.y), bf2f(u2.z), bf2f(u2.w));
            pb16 += N_DIM;
        } else {
            v1 = *(const float4*)(pf);
            v2 = *(const float4*)(pf + H_DIM);
            pf += N_DIM;
        }
        CSTEP(a.x, b.x, h1.x, h2.x, v1.x, v2.x);
        CSTEP(a.y, b.y, h1.y, h2.y, v1.y, v2.y);
        CSTEP(a.z, b.z, h1.z, h2.z, v1.z, v2.z);
        CSTEP(a.w, b.w, h1.w, h2.w, v1.w, v2.w);
    }
    *(float4*)(E + (size_t)c * N_DIM + h4)         = h1;
    *(float4*)(E + (size_t)c * N_DIM + H_DIM + h4) = h2;
}

// ---------------- kernel 4b: scan carries across chunks ----------------

__global__ void scanB(const float* __restrict__ pa, const float* __restrict__ pb,
                      const float* __restrict__ E, float* __restrict__ P) {
    int h = blockIdx.x * 256 + threadIdx.x;
    float a = pa[h], b = pb[h];
    float wr = a, wi = b;                 // w^CHUNK via LOG2_CHUNK complex squarings
#pragma unroll
    for (int i = 0; i < LOG2_CHUNK; i++) {
        float nr = wr * wr - wi * wi;
        float ni = 2.f * wr * wi;
        wr = nr; wi = ni;
    }
    float p1 = 0.f, p2 = 0.f;
#pragma unroll 4
    for (int c = 0; c < NCH; c++) {
        P[(size_t)c * N_DIM + h]         = p1;
        P[(size_t)c * N_DIM + H_DIM + h] = p2;
        float e1 = E[(size_t)c * N_DIM + h];
        float e2 = E[(size_t)c * N_DIM + H_DIM + h];
        float n1 = wr * p1 - wi * p2 + e1;
        float n2 = wr * p2 + wi * p1 + e2;
        p1 = n1; p2 = n2;
    }
}

// ---------------- kernel 4c: final scan with carry-in, 4 channels/thread ----------------

template <bool BF16IN>
__global__ void scanC(const void* __restrict__ v,        // bf16 (ws) or fp32 (== out)
                      float* __restrict__ out,
                      const float* __restrict__ pa, const float* __restrict__ pb,
                      const float* __restrict__ P) {
    int h4 = (blockIdx.x * 256 + threadIdx.x) * 4;
    int c = blockIdx.y;
    float4 a = *(const float4*)(pa + h4);
    float4 b = *(const float4*)(pb + h4);
    float4 h1 = *(const float4*)(P + (size_t)c * N_DIM + h4);
    float4 h2 = *(const float4*)(P + (size_t)c * N_DIM + H_DIM + h4);
    const unsigned short* pb16 = (const unsigned short*)v + (size_t)c * CHUNK * N_DIM + h4;
    const float* pf = (const float*)v + (size_t)c * CHUNK * N_DIM + h4;
    float* po = out + (size_t)c * CHUNK * N_DIM + h4;
#pragma unroll 8
    for (int t = 0; t < CHUNK; t++) {
        float4 v1, v2;
        if (BF16IN) {
            ushort4 u1 = *(const ushort4*)(pb16);
            ushort4 u2 = *(const ushort4*)(pb16 + H_DIM);
            v1 = make_float4(bf2f(u1.x), bf2f(u1.y), bf2f(u1.z), bf2f(u1.w));
            v2 = make_float4(bf2f(u2.x), bf2f(u2.y), bf2f(u2.z), bf2f(u2.w));
            pb16 += N_DIM;
        } else {
            v1 = *(const float4*)(pf);
            v2 = *(const float4*)(pf + H_DIM);
            pf += N_DIM;
        }
        CSTEP(a.x, b.x, h1.x, h2.x, v1.x, v2.x);
        CSTEP(a.y, b.y, h1.y, h2.y, v1.y, v2.y);
        CSTEP(a.z, b.z, h1.z, h2.z, v1.z, v2.z);
        CSTEP(a.w, b.w, h1.w, h2.w, v1.w, v2.w);
        *(float4*)(po)         = h1;
        *(float4*)(po + H_DIM) = h2;
        po += N_DIM;
    }
}

// ---------------- launcher ----------------
// ws layout (bf16 path, 89 MB needed):
//   [0, 16MB)    xb (bf16 x)            -- read only by gemm
//   [0, 4MB)     E   (aliases xb; written by scanA AFTER gemm is done -- same stream)
//   [4MB, 8MB)   P   (aliases xb; written by scanB after scanA)
//   [16MB, 24MB) Bb (bf16 B1|B2)
//   [24MB, +24KB) pa, pb, pg
//   [25MB, 89MB) vb (bf16 v)

extern "C" void kernel_launch(void* const* d_in, const int* in_sizes, int n_in,
                              void* d_out, int out_size, void* d_ws, size_t ws_size,
                              hipStream_t stream) {
    const float* x     = (const float*)d_in[0];   // [T, D]
    const float* lamda = (const float*)d_in[1];   // [H]
    const float* theta = (const float*)d_in[2];   // [H]
    const float* B1    = (const float*)d_in[3];   // [H, D]
    const float* B2    = (const float*)d_in[4];   // [H, D]
    float* out = (float*)d_out;                   // [T, 2H]

    char* ws = (char*)d_ws;
    unsigned short* xb = (unsigned short*)ws;                              // 16 MB
    float* E  = (float*)ws;                                                // 4 MB (aliases xb)
    float* P  = (float*)(ws + (size_t)4 * 1024 * 1024);                    // 4 MB (aliases xb)
    unsigned short* Bb = (unsigned short*)(ws + (size_t)16 * 1024 * 1024); // 8 MB
    float* pa = (float*)(ws + (size_t)24 * 1024 * 1024);
    float* pb = pa + H_DIM;
    float* pg = pb + H_DIM;
    unsigned short* vb = (unsigned short*)(ws + (size_t)25 * 1024 * 1024); // 64 MB
    const size_t need_bf16 = (size_t)25 * 1024 * 1024 + (size_t)T_DIM * N_DIM * 2;
    const bool use_bf16 = (ws_size >= need_bf16);

    // 1. params
    hipLaunchKernelGGL(params_kernel, dim3(H_DIM / 256), dim3(256), 0, stream,
                       lamda, theta, pa, pb, pg);
    // 2. converts (single launch)
    {
        int n0 = T_DIM * D_DIM / 4, n1 = H_DIM * D_DIM / 4, n2 = n1;
        int blocks = (n0 + n1 + n2 + 255) / 256;
        hipLaunchKernelGGL(cvt3_kernel, dim3(blocks), dim3(256), 0, stream,
                           (const float4*)x, (ushort4*)xb, n0,
                           (const float4*)B1, (ushort4*)Bb, n1,
                           (const float4*)B2, (ushort4*)(Bb + (size_t)H_DIM * D_DIM), n2);
    }
    // 3. GEMM: v (gamma-scaled) -> bf16 ws buffer (preferred) or fp32 d_out
    void* vptr = use_bf16 ? (void*)vb : (void*)out;
    if (use_bf16)
        gemm_bt<true><<<dim3(T_DIM / 128, N_DIM / 128), dim3(256), 0, stream>>>(xb, Bb, pg, vptr);
    else
        gemm_bt<false><<<dim3(T_DIM / 128, N_DIM / 128), dim3(256), 0, stream>>>(xb, Bb, pg, vptr);
    // 4. chunked scan
    dim3 sgrid(H_DIM / 4 / 256, NCH);
    if (use_bf16) {
        scanA<true><<<sgrid, dim3(256), 0, stream>>>(vptr, pa, pb, E);
    } else {
        scanA<false><<<sgrid, dim3(256), 0, stream>>>(vptr, pa, pb, E);
    }
    hipLaunchKernelGGL(scanB, dim3(H_DIM / 256), dim3(256), 0, stream, pa, pb, E, P);
    if (use_bf16) {
        scanC<true><<<sgrid, dim3(256), 0, stream>>>(vptr, out, pa, pb, P);
    } else {
        scanC<false><<<sgrid, dim3(256), 0, stream>>>(vptr, out, pa, pb, P);
    }
}

// Round 5
// 307.347 us; speedup vs baseline: 1.1103x; 1.1103x over previous
//
#include <hip/hip_runtime.h>

#define T_DIM 8192
#define D_DIM 1024
#define H_DIM 2048
#define N_DIM 4096
#define CHUNK 32
#define LOG2_CHUNK 5
#define NCH   (T_DIM / CHUNK)   // 256

typedef __attribute__((ext_vector_type(8))) short bf16x8;
typedef __attribute__((ext_vector_type(4))) float f32x4;

// ---------------- helpers ----------------

__device__ __forceinline__ unsigned short f2bf(float f) {
    unsigned int u = __float_as_uint(f);
    unsigned int r = (u + 0x7fffu + ((u >> 16) & 1u)) >> 16;  // RNE
    return (unsigned short)r;
}

__device__ __forceinline__ float blo(unsigned int u) { return __uint_as_float(u << 16); }
__device__ __forceinline__ float bhi(unsigned int u) { return __uint_as_float(u & 0xffff0000u); }

__device__ __forceinline__ void gl_lds16(const unsigned short* g, unsigned short* l) {
    __builtin_amdgcn_global_load_lds(
        (__attribute__((address_space(1))) void*)(g),
        (__attribute__((address_space(3))) void*)(l), 16, 0, 0);
}

// complex rotate-accumulate: (H1+iH2) = (A+iB)(H1+iH2) + (V1+iV2)
#define CSTEP(A, Bq, H1, H2, V1, V2)                  \
    {                                                 \
        float n1 = (A) * (H1) - (Bq) * (H2) + (V1);   \
        float n2 = (A) * (H2) + (Bq) * (H1) + (V2);   \
        (H1) = n1; (H2) = n2;                         \
    }

// ---------------- kernel 1: per-channel params ----------------

__global__ void params_kernel(const float* __restrict__ lamda,
                              const float* __restrict__ theta,
                              float* __restrict__ pa, float* __restrict__ pb,
                              float* __restrict__ pg) {
    int h = blockIdx.x * 256 + threadIdx.x;
    if (h >= H_DIM) return;
    float y = expf(-expf(lamda[h]));
    float z = expf(theta[h]);
    pg[h] = sqrtf(1.0f - y * y);
    pa[h] = y * cosf(z);
    pb[h] = y * sinf(z);
}

// ---------------- kernel 2: fused fp32 -> bf16 convert (x, B1, B2) ----------------

__global__ void cvt3_kernel(const float4* __restrict__ s0, ushort4* __restrict__ d0, int n0,
                            const float4* __restrict__ s1, ushort4* __restrict__ d1, int n1,
                            const float4* __restrict__ s2, ushort4* __restrict__ d2, int n2) {
    int i = blockIdx.x * 256 + threadIdx.x;
    const float4* s; ushort4* d; int j;
    if (i < n0)                { s = s0; d = d0; j = i; }
    else if (i < n0 + n1)      { s = s1; d = d1; j = i - n0; }
    else if (i < n0 + n1 + n2) { s = s2; d = d2; j = i - n0 - n1; }
    else return;
    float4 f = s[j];
    ushort4 o;
    o.x = f2bf(f.x); o.y = f2bf(f.y); o.z = f2bf(f.z); o.w = f2bf(f.w);
    d[j] = o;
}

// ---------------- kernel 3: bf16 GEMM (A[M,K] x B[N,K]^T), gamma epilogue ----------------
// 128x128 tile, BK=32, 4 waves (2x2), 4x4 MFMA 16x16x32 per wave.
// Global-side XOR swizzle of the k-group breaks LDS bank conflicts (R2: 8.4M -> 0).

template <bool BF16OUT>
__global__ __launch_bounds__(256) void gemm_bt(
    const unsigned short* __restrict__ A,   // [8192,1024] bf16
    const unsigned short* __restrict__ B,   // [4096,1024] bf16
    const float* __restrict__ gamma,        // [2048]
    void* __restrict__ Cv)                  // [8192,4096] fp32 or bf16
{
    __shared__ unsigned short sA[128 * 32];
    __shared__ unsigned short sB[128 * 32];

    const int tid  = threadIdx.x;
    const int lane = tid & 63;
    const int wave = tid >> 6;
    const int quad = lane >> 4;
    const int m16  = lane & 15;
    const int wm = (wave >> 1) << 6;
    const int wn = (wave & 1) << 6;

    const int rowA0 = blockIdx.x * 128;
    const int rowB0 = blockIdx.y * 128;

    const int e0 = tid * 8;
    const int r0 = e0 >> 5;
    const int gs = (e0 >> 3) & 3;
    const int k0 = (gs ^ ((r0 >> 1) & 3)) * 8;
    const int r1 = r0 + 64;

    const unsigned short* a0 = A + (size_t)(rowA0 + r0) * D_DIM + k0;
    const unsigned short* a1 = A + (size_t)(rowA0 + r1) * D_DIM + k0;
    const unsigned short* b0 = B + (size_t)(rowB0 + r0) * D_DIM + k0;
    const unsigned short* b1 = B + (size_t)(rowB0 + r1) * D_DIM + k0;
    unsigned short* la0 = &sA[e0];
    unsigned short* la1 = &sA[e0 + 2048];
    unsigned short* lb0 = &sB[e0];
    unsigned short* lb1 = &sB[e0 + 2048];

    const int grp8 = (quad ^ ((m16 >> 1) & 3)) * 8;

    f32x4 acc[4][4];
#pragma unroll
    for (int i = 0; i < 4; i++)
#pragma unroll
        for (int j = 0; j < 4; j++) acc[i][j] = (f32x4)(0.0f);

    for (int kt = 0; kt < D_DIM; kt += 32) {
        __syncthreads();
        gl_lds16(a0 + kt, la0);
        gl_lds16(a1 + kt, la1);
        gl_lds16(b0 + kt, lb0);
        gl_lds16(b1 + kt, lb1);
        __syncthreads();

        bf16x8 af[4], bfr[4];
#pragma unroll
        for (int i = 0; i < 4; i++)
            af[i] = *(const bf16x8*)&sA[(wm + i * 16 + m16) * 32 + grp8];
#pragma unroll
        for (int i = 0; i < 4; i++)
            bfr[i] = *(const bf16x8*)&sB[(wn + i * 16 + m16) * 32 + grp8];

#pragma unroll
        for (int mi = 0; mi < 4; mi++)
#pragma unroll
            for (int ni = 0; ni < 4; ni++)
                acc[mi][ni] = __builtin_amdgcn_mfma_f32_16x16x32_bf16(
                    af[mi], bfr[ni], acc[mi][ni], 0, 0, 0);
    }

    float* Cf = (float*)Cv;
    unsigned short* Cb = (unsigned short*)Cv;
#pragma unroll
    for (int ni = 0; ni < 4; ni++) {
        const int col = rowB0 + wn + ni * 16 + m16;
        const float g = gamma[col & (H_DIM - 1)];
#pragma unroll
        for (int mi = 0; mi < 4; mi++) {
            const int row0 = rowA0 + wm + mi * 16 + quad * 4;
#pragma unroll
            for (int r = 0; r < 4; r++) {
                float val = acc[mi][ni][r] * g;
                if (BF16OUT)
                    Cb[(size_t)(row0 + r) * N_DIM + col] = f2bf(val);
                else
                    Cf[(size_t)(row0 + r) * N_DIM + col] = val;
            }
        }
    }
}

// ---------------- kernel 4a: chunk-local end states, 4 channels/thread ----------------

template <bool BF16IN>
__global__ void scanA(const void* __restrict__ v,        // [T, 4096] bf16 or fp32
                      const float* __restrict__ pa, const float* __restrict__ pb,
                      float* __restrict__ E)             // [NCH][4096]
{
    int h4 = (blockIdx.x * 256 + threadIdx.x) * 4;
    int c = blockIdx.y;
    float4 a = *(const float4*)(pa + h4);
    float4 b = *(const float4*)(pb + h4);
    float4 h1 = make_float4(0.f, 0.f, 0.f, 0.f);
    float4 h2 = make_float4(0.f, 0.f, 0.f, 0.f);
    const unsigned short* pb16 = (const unsigned short*)v + (size_t)c * CHUNK * N_DIM + h4;
    const float* pf = (const float*)v + (size_t)c * CHUNK * N_DIM + h4;
#pragma unroll 8
    for (int t = 0; t < CHUNK; t++) {
        float4 v1, v2;
        if (BF16IN) {
            uint2 u1 = *(const uint2*)(pb16);
            uint2 u2 = *(const uint2*)(pb16 + H_DIM);
            v1 = make_float4(blo(u1.x), bhi(u1.x), blo(u1.y), bhi(u1.y));
            v2 = make_float4(blo(u2.x), bhi(u2.x), blo(u2.y), bhi(u2.y));
            pb16 += N_DIM;
        } else {
            v1 = *(const float4*)(pf);
            v2 = *(const float4*)(pf + H_DIM);
            pf += N_DIM;
        }
        CSTEP(a.x, b.x, h1.x, h2.x, v1.x, v2.x);
        CSTEP(a.y, b.y, h1.y, h2.y, v1.y, v2.y);
        CSTEP(a.z, b.z, h1.z, h2.z, v1.z, v2.z);
        CSTEP(a.w, b.w, h1.w, h2.w, v1.w, v2.w);
    }
    *(float4*)(E + (size_t)c * N_DIM + h4)         = h1;
    *(float4*)(E + (size_t)c * N_DIM + H_DIM + h4) = h2;
}

// ---------------- kernel 4b: wave-parallel carry scan ----------------
// 512 blocks x 256 thr; one WAVE per channel (2048 waves). Lane l composes
// chunks 4l..4l+3, then a weighted shfl_up scan (ratio W^4*2^j) yields all
// carry-ins. Replaces the 256-iteration serial scanB (latency-bound, ~30us).

__global__ __launch_bounds__(256) void scanB_wave(
    const float* __restrict__ pa, const float* __restrict__ pb,
    const float* __restrict__ E, float* __restrict__ P) {
    const int lane = threadIdx.x & 63;
    const int ch   = blockIdx.x * 4 + (threadIdx.x >> 6);   // 0..2047
    const float ca = pa[ch], cb = pb[ch];
    // W = w^CHUNK via LOG2_CHUNK complex squarings
    float Wr = ca, Wi = cb;
#pragma unroll
    for (int j = 0; j < LOG2_CHUNK; j++) {
        float nr = Wr * Wr - Wi * Wi, ni = 2.f * Wr * Wi;
        Wr = nr; Wi = ni;
    }
    // lane-local inclusive compose over 4 chunks
    float Sr[4], Si[4];
    float sr = 0.f, si = 0.f;
#pragma unroll
    for (int k = 0; k < 4; k++) {
        int cc = 4 * lane + k;
        float e1 = E[(size_t)cc * N_DIM + ch];
        float e2 = E[(size_t)cc * N_DIM + H_DIM + ch];
        float nr = Wr * sr - Wi * si + e1;
        float ni = Wr * si + Wi * sr + e2;
        sr = nr; si = ni;
        Sr[k] = sr; Si[k] = si;
    }
    // wave inclusive scan of lane totals with ratio W^4
    float vr = sr, vi = si;
    float W4r = Wr * Wr - Wi * Wi, W4i = 2.f * Wr * Wi;      // W^2
    { float nr = W4r * W4r - W4i * W4i, ni = 2.f * W4r * W4i; // W^4
      W4r = nr; W4i = ni; }
    float stepR = W4r, stepI = W4i;
#pragma unroll
    for (int d = 1; d < 64; d <<= 1) {
        float tr = __shfl_up(vr, d, 64);
        float ti = __shfl_up(vi, d, 64);
        float nr = stepR * tr - stepI * ti + vr;
        float ni = stepR * ti + stepI * tr + vi;
        if (lane >= d) { vr = nr; vi = ni; }
        float r2 = stepR * stepR - stepI * stepI;
        float i2 = 2.f * stepR * stepI;
        stepR = r2; stepI = i2;
    }
    // exclusive over lanes -> carry-in of chunk 4l
    float txr = __shfl_up(vr, 1, 64);
    float txi = __shfl_up(vi, 1, 64);
    if (lane == 0) { txr = 0.f; txi = 0.f; }
    P[(size_t)(4 * lane) * N_DIM + ch]         = txr;
    P[(size_t)(4 * lane) * N_DIM + H_DIM + ch] = txi;
    float qr = txr, qi = txi;
#pragma unroll
    for (int k = 1; k < 4; k++) {
        float nr = Wr * qr - Wi * qi;
        float ni = Wr * qi + Wi * qr;
        qr = nr; qi = ni;
        P[(size_t)(4 * lane + k) * N_DIM + ch]         = qr + Sr[k - 1];
        P[(size_t)(4 * lane + k) * N_DIM + H_DIM + ch] = qi + Si[k - 1];
    }
}

// ---------------- kernel 4c: final scan with carry-in, NT stores ----------------

template <bool BF16IN>
__global__ void scanC(const void* __restrict__ v,        // bf16 (ws) or fp32 (== out)
                      float* __restrict__ out,
                      const float* __restrict__ pa, const float* __restrict__ pb,
                      const float* __restrict__ P) {
    int h4 = (blockIdx.x * 256 + threadIdx.x) * 4;
    int c = blockIdx.y;
    f32x4 a = *(const f32x4*)(pa + h4);
    f32x4 b = *(const f32x4*)(pb + h4);
    f32x4 h1 = *(const f32x4*)(P + (size_t)c * N_DIM + h4);
    f32x4 h2 = *(const f32x4*)(P + (size_t)c * N_DIM + H_DIM + h4);
    const unsigned short* pb16 = (const unsigned short*)v + (size_t)c * CHUNK * N_DIM + h4;
    const float* pf = (const float*)v + (size_t)c * CHUNK * N_DIM + h4;
    float* po = out + (size_t)c * CHUNK * N_DIM + h4;
#pragma unroll 8
    for (int t = 0; t < CHUNK; t++) {
        f32x4 v1, v2;
        if (BF16IN) {
            uint2 u1 = *(const uint2*)(pb16);
            uint2 u2 = *(const uint2*)(pb16 + H_DIM);
            v1 = (f32x4){blo(u1.x), bhi(u1.x), blo(u1.y), bhi(u1.y)};
            v2 = (f32x4){blo(u2.x), bhi(u2.x), blo(u2.y), bhi(u2.y)};
            pb16 += N_DIM;
        } else {
            v1 = *(const f32x4*)(pf);
            v2 = *(const f32x4*)(pf + H_DIM);
            pf += N_DIM;
        }
        CSTEP(a.x, b.x, h1.x, h2.x, v1.x, v2.x);
        CSTEP(a.y, b.y, h1.y, h2.y, v1.y, v2.y);
        CSTEP(a.z, b.z, h1.z, h2.z, v1.z, v2.z);
        CSTEP(a.w, b.w, h1.w, h2.w, v1.w, v2.w);
        __builtin_nontemporal_store(h1, (f32x4*)(po));
        __builtin_nontemporal_store(h2, (f32x4*)(po + H_DIM));
        po += N_DIM;
    }
}

// ---------------- launcher ----------------
// ws layout (bf16 path, needs 25MB + 64MiB):
//   [0, 4MB)     E (aliases xb region; written after gemm is done reading xb)
//   [4MB, 8MB)   P (aliases xb)
//   [0, 16MB)    xb (bf16 x) -- read only by gemm
//   [16MB, 24MB) Bb (bf16 B1|B2)
//   [24MB, ..)   pa, pb, pg
//   [25MB, ..)   vb (bf16 v, 64 MiB)

extern "C" void kernel_launch(void* const* d_in, const int* in_sizes, int n_in,
                              void* d_out, int out_size, void* d_ws, size_t ws_size,
                              hipStream_t stream) {
    const float* x     = (const float*)d_in[0];
    const float* lamda = (const float*)d_in[1];
    const float* theta = (const float*)d_in[2];
    const float* B1    = (const float*)d_in[3];
    const float* B2    = (const float*)d_in[4];
    float* out = (float*)d_out;

    char* ws = (char*)d_ws;
    unsigned short* xb = (unsigned short*)ws;                              // 16 MB
    float* E  = (float*)ws;                                                // 4 MB (aliases xb)
    float* P  = (float*)(ws + (size_t)4 * 1024 * 1024);                    // 4 MB (aliases xb)
    unsigned short* Bb = (unsigned short*)(ws + (size_t)16 * 1024 * 1024); // 8 MB
    float* pa = (float*)(ws + (size_t)24 * 1024 * 1024);
    float* pb = pa + H_DIM;
    float* pg = pb + H_DIM;
    unsigned short* vb = (unsigned short*)(ws + (size_t)25 * 1024 * 1024); // 64 MiB
    const size_t need_bf16 = (size_t)25 * 1024 * 1024 + (size_t)T_DIM * N_DIM * 2;
    const bool use_bf16 = (ws_size >= need_bf16);

    hipLaunchKernelGGL(params_kernel, dim3(H_DIM / 256), dim3(256), 0, stream,
                       lamda, theta, pa, pb, pg);
    {
        int n0 = T_DIM * D_DIM / 4, n1 = H_DIM * D_DIM / 4, n2 = n1;
        int blocks = (n0 + n1 + n2 + 255) / 256;
        hipLaunchKernelGGL(cvt3_kernel, dim3(blocks), dim3(256), 0, stream,
                           (const float4*)x, (ushort4*)xb, n0,
                           (const float4*)B1, (ushort4*)Bb, n1,
                           (const float4*)B2, (ushort4*)(Bb + (size_t)H_DIM * D_DIM), n2);
    }

    dim3 sgrid(H_DIM / 4 / 256, NCH);   // (2, 256)
    if (use_bf16) {
        gemm_bt<true><<<dim3(T_DIM / 128, N_DIM / 128), dim3(256), 0, stream>>>(xb, Bb, pg, (void*)vb);
        scanA<true><<<sgrid, dim3(256), 0, stream>>>(vb, pa, pb, E);
        hipLaunchKernelGGL(scanB_wave, dim3(H_DIM / 4), dim3(256), 0, stream, pa, pb, E, P);
        scanC<true><<<sgrid, dim3(256), 0, stream>>>(vb, out, pa, pb, P);
    } else {
        gemm_bt<false><<<dim3(T_DIM / 128, N_DIM / 128), dim3(256), 0, stream>>>(xb, Bb, pg, (void*)out);
        scanA<false><<<sgrid, dim3(256), 0, stream>>>(out, pa, pb, E);
        hipLaunchKernelGGL(scanB_wave, dim3(H_DIM / 4), dim3(256), 0, stream, pa, pb, E, P);
        scanC<false><<<sgrid, dim3(256), 0, stream>>>(out, out, pa, pb, P);
    }
}

// Round 6
// 286.491 us; speedup vs baseline: 1.1911x; 1.0728x over previous
//
#include <hip/hip_runtime.h>

#define T_DIM 8192
#define D_DIM 1024
#define H_DIM 2048
#define N_DIM 4096
#define CHUNK 32
#define LOG2_CHUNK 5
#define NCH   (T_DIM / CHUNK)   // 256
#define TSTR  136               // LDS tile stride (ushorts); 136*2=272=17*16 -> 16B-aligned rows

typedef __attribute__((ext_vector_type(8))) short bf16x8;
typedef __attribute__((ext_vector_type(4))) float f32x4;

// ---------------- helpers ----------------

__device__ __forceinline__ unsigned short f2bf(float f) {
    unsigned int u = __float_as_uint(f);
    unsigned int r = (u + 0x7fffu + ((u >> 16) & 1u)) >> 16;  // RNE
    return (unsigned short)r;
}

__device__ __forceinline__ float blo(unsigned int u) { return __uint_as_float(u << 16); }
__device__ __forceinline__ float bhi(unsigned int u) { return __uint_as_float(u & 0xffff0000u); }
__device__ __forceinline__ float bf2f(unsigned short u) {
    return __uint_as_float((unsigned int)u << 16);
}

__device__ __forceinline__ void gl_lds16(const unsigned short* g, unsigned short* l) {
    __builtin_amdgcn_global_load_lds(
        (__attribute__((address_space(1))) void*)(g),
        (__attribute__((address_space(3))) void*)(l), 16, 0, 0);
}

// complex rotate-accumulate: (H1+iH2) = (A+iB)(H1+iH2) + (V1+iV2)
#define CSTEP(A, Bq, H1, H2, V1, V2)                  \
    {                                                 \
        float n1 = (A) * (H1) - (Bq) * (H2) + (V1);   \
        float n2 = (A) * (H2) + (Bq) * (H1) + (V2);   \
        (H1) = n1; (H2) = n2;                         \
    }

// ---------------- kernel 1: per-channel params ----------------

__global__ void params_kernel(const float* __restrict__ lamda,
                              const float* __restrict__ theta,
                              float* __restrict__ pa, float* __restrict__ pb,
                              float* __restrict__ pg) {
    int h = blockIdx.x * 256 + threadIdx.x;
    if (h >= H_DIM) return;
    float y = expf(-expf(lamda[h]));
    float z = expf(theta[h]);
    pg[h] = sqrtf(1.0f - y * y);
    pa[h] = y * cosf(z);
    pb[h] = y * sinf(z);
}

// ---------------- kernel 2a: x fp32->bf16 ----------------

__global__ void cvt_x(const float4* __restrict__ s, ushort4* __restrict__ d, int n4) {
    int i = blockIdx.x * 256 + threadIdx.x;
    if (i >= n4) return;
    float4 f = s[i];
    ushort4 o;
    o.x = f2bf(f.x); o.y = f2bf(f.y); o.z = f2bf(f.z); o.w = f2bf(f.w);
    d[i] = o;
}

// ---------------- kernel 2b: B1/B2 fp32->bf16, optional channel-interleave ----------------
// inter=1: dest tile layout [32][128][1024]: tile q rows 0..63 = B1[q*64..], rows 64..127 = B2[q*64..]
// inter=0: contiguous [B1; B2] (fallback path)

__global__ void cvt_B(const float4* __restrict__ s1, const float4* __restrict__ s2,
                      ushort4* __restrict__ d, int inter) {
    const int n = H_DIM * D_DIM / 4;   // groups per matrix
    int i = blockIdx.x * 256 + threadIdx.x;
    const float4* s; int comp, j;
    if (i < n) { s = s1; comp = 0; j = i; }
    else if (i < 2 * n) { s = s2; comp = 1; j = i - n; }
    else return;
    float4 f = s[j];
    ushort4 o;
    o.x = f2bf(f.x); o.y = f2bf(f.y); o.z = f2bf(f.z); o.w = f2bf(f.w);
    int h = j >> 8;          // 256 float4-groups per 1024-row
    int d4 = j & 255;
    int drow = inter ? ((h >> 6) * 128 + (comp << 6) + (h & 63))
                     : (comp * H_DIM + h);
    d[(size_t)drow * 256 + d4] = o;
}

// ---------------- kernel 3 (fused path): GEMM + gamma + chunk-local scan epilogue ----
// Grid (64, 32). Block computes 128 timesteps x (64 channels x 2 comps) using the
// interleaved B. Epilogue: acc -> LDS tile (bf16, XOR-swizzled), 4 chunk scans emit E,
// tile streamed to V with full-line 16B stores.

__global__ __launch_bounds__(256) void gemm_fused(
    const unsigned short* __restrict__ A,    // [8192,1024] bf16
    const unsigned short* __restrict__ Bi,   // interleaved [32*128,1024] bf16
    const float* __restrict__ gamma,         // [2048]
    const float* __restrict__ pa, const float* __restrict__ pb,
    unsigned short* __restrict__ V,          // bf16 [8192][4096]
    float* __restrict__ E)                   // [256][4096]
{
    __shared__ unsigned short smem[128 * TSTR];   // 34816 B; sA/sB alias the front
    unsigned short* sA = smem;            // 8 KB
    unsigned short* sB = smem + 4096;     // 8 KB

    const int tid  = threadIdx.x;
    const int lane = tid & 63;
    const int wave = tid >> 6;
    const int quad = lane >> 4;
    const int m16  = lane & 15;
    const int wm = (wave >> 1) << 6;
    const int wn = (wave & 1) << 6;

    const int rowA0 = blockIdx.x * 128;
    const int rowB0 = blockIdx.y * 128;
    const int ch0   = blockIdx.y * 64;

    const int e0 = tid * 8;
    const int r0 = e0 >> 5;
    const int gs = (e0 >> 3) & 3;
    const int k0 = (gs ^ ((r0 >> 1) & 3)) * 8;   // k-group XOR swizzle (R2: conflicts -> 0)
    const int r1 = r0 + 64;

    const unsigned short* a0 = A + (size_t)(rowA0 + r0) * D_DIM + k0;
    const unsigned short* a1 = A + (size_t)(rowA0 + r1) * D_DIM + k0;
    const unsigned short* b0 = Bi + (size_t)(rowB0 + r0) * D_DIM + k0;
    const unsigned short* b1 = Bi + (size_t)(rowB0 + r1) * D_DIM + k0;
    unsigned short* la0 = &sA[e0];
    unsigned short* la1 = &sA[e0 + 2048];
    unsigned short* lb0 = &sB[e0];
    unsigned short* lb1 = &sB[e0 + 2048];

    const int grp8 = (quad ^ ((m16 >> 1) & 3)) * 8;

    f32x4 acc[4][4];
#pragma unroll
    for (int i = 0; i < 4; i++)
#pragma unroll
        for (int j = 0; j < 4; j++) acc[i][j] = (f32x4)(0.0f);

    for (int kt = 0; kt < D_DIM; kt += 32) {
        __syncthreads();
        gl_lds16(a0 + kt, la0);
        gl_lds16(a1 + kt, la1);
        gl_lds16(b0 + kt, lb0);
        gl_lds16(b1 + kt, lb1);
        __syncthreads();

        bf16x8 af[4], bfr[4];
#pragma unroll
        for (int i = 0; i < 4; i++)
            af[i] = *(const bf16x8*)&sA[(wm + i * 16 + m16) * 32 + grp8];
#pragma unroll
        for (int i = 0; i < 4; i++)
            bfr[i] = *(const bf16x8*)&sB[(wn + i * 16 + m16) * 32 + grp8];

#pragma unroll
        for (int mi = 0; mi < 4; mi++)
#pragma unroll
            for (int ni = 0; ni < 4; ni++)
                acc[mi][ni] = __builtin_amdgcn_mfma_f32_16x16x32_bf16(
                    af[mi], bfr[ni], acc[mi][ni], 0, 0, 0);
    }

    __syncthreads();   // all K-loop LDS reads done before tile overwrite

    // ---- acc -> LDS tile (bf16, gamma-scaled) ----
    // C/D layout: col = wn+ni*16+m16, t = wm+mi*16+quad*4+r
    // swizzle sw(t) = (((t>>2)&3)*48)&63 -> quads land on bank quarters {0,8,16,24}: 2-way only
#pragma unroll
    for (int ni = 0; ni < 4; ni++) {
        const int col = wn + ni * 16 + m16;
        const float g = gamma[ch0 + (col & 63)];
#pragma unroll
        for (int mi = 0; mi < 4; mi++) {
#pragma unroll
            for (int r = 0; r < 4; r++) {
                const int t  = wm + mi * 16 + quad * 4 + r;
                const int sw = (((t >> 2) & 3) * 48) & 63;
                smem[t * TSTR + (col ^ sw)] = f2bf(acc[mi][ni][r] * g);
            }
        }
    }
    __syncthreads();

    // ---- chunk-local scans: thread = (channel, chunk) ----
    {
        const int chl = tid & 63;
        const int ck  = tid >> 6;          // 0..3
        const float wa = pa[ch0 + chl], wb = pb[ch0 + chl];
        float e1 = 0.f, e2 = 0.f;
#pragma unroll
        for (int j = 0; j < CHUNK; j++) {
            const int t  = ck * CHUNK + j;
            const int sw = (((t >> 2) & 3) * 48) & 63;   // wave-uniform (t uniform per wave)
            float v1 = bf2f(smem[t * TSTR + (chl ^ sw)]);
            float v2 = bf2f(smem[t * TSTR + ((64 + chl) ^ sw)]);
            CSTEP(wa, wb, e1, e2, v1, v2);
        }
        const int cg = blockIdx.x * 4 + ck;
        E[(size_t)cg * N_DIM + ch0 + chl]         = e1;
        E[(size_t)cg * N_DIM + H_DIM + ch0 + chl] = e2;
    }

    // ---- stream tile -> V (bf16, 16B stores). sw multiples of 16 preserve 8-ushort groups.
#pragma unroll
    for (int s = 0; s < 8; s++) {
        const int g   = s * 256 + tid;
        const int row = g >> 4;
        const int seg = (g >> 3) & 1;
        const int k   = g & 7;
        const int sw  = (((row >> 2) & 3) * 48) & 63;
        uint4 val = *(const uint4*)&smem[row * TSTR + ((seg * 64 + k * 8) ^ sw)];
        *(uint4*)&V[(size_t)(rowA0 + row) * N_DIM + seg * H_DIM + ch0 + k * 8] = val;
    }
}

// ---------------- kernel 3 (fallback): R5 gemm ----------------

template <bool BF16OUT>
__global__ __launch_bounds__(256) void gemm_bt(
    const unsigned short* __restrict__ A, const unsigned short* __restrict__ B,
    const float* __restrict__ gamma, void* __restrict__ Cv)
{
    __shared__ unsigned short sA[128 * 32];
    __shared__ unsigned short sB[128 * 32];

    const int tid  = threadIdx.x;
    const int lane = tid & 63;
    const int wave = tid >> 6;
    const int quad = lane >> 4;
    const int m16  = lane & 15;
    const int wm = (wave >> 1) << 6;
    const int wn = (wave & 1) << 6;
    const int rowA0 = blockIdx.x * 128;
    const int rowB0 = blockIdx.y * 128;
    const int e0 = tid * 8;
    const int r0 = e0 >> 5;
    const int gs = (e0 >> 3) & 3;
    const int k0 = (gs ^ ((r0 >> 1) & 3)) * 8;
    const int r1 = r0 + 64;
    const unsigned short* a0 = A + (size_t)(rowA0 + r0) * D_DIM + k0;
    const unsigned short* a1 = A + (size_t)(rowA0 + r1) * D_DIM + k0;
    const unsigned short* b0 = B + (size_t)(rowB0 + r0) * D_DIM + k0;
    const unsigned short* b1 = B + (size_t)(rowB0 + r1) * D_DIM + k0;
    unsigned short* la0 = &sA[e0];
    unsigned short* la1 = &sA[e0 + 2048];
    unsigned short* lb0 = &sB[e0];
    unsigned short* lb1 = &sB[e0 + 2048];
    const int grp8 = (quad ^ ((m16 >> 1) & 3)) * 8;

    f32x4 acc[4][4];
#pragma unroll
    for (int i = 0; i < 4; i++)
#pragma unroll
        for (int j = 0; j < 4; j++) acc[i][j] = (f32x4)(0.0f);

    for (int kt = 0; kt < D_DIM; kt += 32) {
        __syncthreads();
        gl_lds16(a0 + kt, la0);
        gl_lds16(a1 + kt, la1);
        gl_lds16(b0 + kt, lb0);
        gl_lds16(b1 + kt, lb1);
        __syncthreads();
        bf16x8 af[4], bfr[4];
#pragma unroll
        for (int i = 0; i < 4; i++)
            af[i] = *(const bf16x8*)&sA[(wm + i * 16 + m16) * 32 + grp8];
#pragma unroll
        for (int i = 0; i < 4; i++)
            bfr[i] = *(const bf16x8*)&sB[(wn + i * 16 + m16) * 32 + grp8];
#pragma unroll
        for (int mi = 0; mi < 4; mi++)
#pragma unroll
            for (int ni = 0; ni < 4; ni++)
                acc[mi][ni] = __builtin_amdgcn_mfma_f32_16x16x32_bf16(
                    af[mi], bfr[ni], acc[mi][ni], 0, 0, 0);
    }

    float* Cf = (float*)Cv;
    unsigned short* Cb = (unsigned short*)Cv;
#pragma unroll
    for (int ni = 0; ni < 4; ni++) {
        const int col = rowB0 + wn + ni * 16 + m16;
        const float g = gamma[col & (H_DIM - 1)];
#pragma unroll
        for (int mi = 0; mi < 4; mi++) {
            const int row0 = rowA0 + wm + mi * 16 + quad * 4;
#pragma unroll
            for (int r = 0; r < 4; r++) {
                float val = acc[mi][ni][r] * g;
                if (BF16OUT) Cb[(size_t)(row0 + r) * N_DIM + col] = f2bf(val);
                else         Cf[(size_t)(row0 + r) * N_DIM + col] = val;
            }
        }
    }
}

// ---------------- kernel 4a (fallback): chunk-local end states ----------------

template <bool BF16IN>
__global__ void scanA(const void* __restrict__ v,
                      const float* __restrict__ pa, const float* __restrict__ pb,
                      float* __restrict__ E) {
    int h4 = (blockIdx.x * 256 + threadIdx.x) * 4;
    int c = blockIdx.y;
    float4 a = *(const float4*)(pa + h4);
    float4 b = *(const float4*)(pb + h4);
    float4 h1 = make_float4(0.f, 0.f, 0.f, 0.f);
    float4 h2 = make_float4(0.f, 0.f, 0.f, 0.f);
    const unsigned short* pb16 = (const unsigned short*)v + (size_t)c * CHUNK * N_DIM + h4;
    const float* pf = (const float*)v + (size_t)c * CHUNK * N_DIM + h4;
#pragma unroll 8
    for (int t = 0; t < CHUNK; t++) {
        float4 v1, v2;
        if (BF16IN) {
            uint2 u1 = *(const uint2*)(pb16);
            uint2 u2 = *(const uint2*)(pb16 + H_DIM);
            v1 = make_float4(blo(u1.x), bhi(u1.x), blo(u1.y), bhi(u1.y));
            v2 = make_float4(blo(u2.x), bhi(u2.x), blo(u2.y), bhi(u2.y));
            pb16 += N_DIM;
        } else {
            v1 = *(const float4*)(pf);
            v2 = *(const float4*)(pf + H_DIM);
            pf += N_DIM;
        }
        CSTEP(a.x, b.x, h1.x, h2.x, v1.x, v2.x);
        CSTEP(a.y, b.y, h1.y, h2.y, v1.y, v2.y);
        CSTEP(a.z, b.z, h1.z, h2.z, v1.z, v2.z);
        CSTEP(a.w, b.w, h1.w, h2.w, v1.w, v2.w);
    }
    *(float4*)(E + (size_t)c * N_DIM + h4)         = h1;
    *(float4*)(E + (size_t)c * N_DIM + H_DIM + h4) = h2;
}

// ---------------- kernel 4b: wave-parallel carry scan (one wave per channel) ----------------

__global__ __launch_bounds__(256) void scanB_wave(
    const float* __restrict__ pa, const float* __restrict__ pb,
    const float* __restrict__ E, float* __restrict__ P) {
    const int lane = threadIdx.x & 63;
    const int ch   = blockIdx.x * 4 + (threadIdx.x >> 6);
    const float ca = pa[ch], cb = pb[ch];
    float Wr = ca, Wi = cb;
#pragma unroll
    for (int j = 0; j < LOG2_CHUNK; j++) {
        float nr = Wr * Wr - Wi * Wi, ni = 2.f * Wr * Wi;
        Wr = nr; Wi = ni;
    }
    float Sr[4], Si[4];
    float sr = 0.f, si = 0.f;
#pragma unroll
    for (int k = 0; k < 4; k++) {
        int cc = 4 * lane + k;
        float e1 = E[(size_t)cc * N_DIM + ch];
        float e2 = E[(size_t)cc * N_DIM + H_DIM + ch];
        float nr = Wr * sr - Wi * si + e1;
        float ni = Wr * si + Wi * sr + e2;
        sr = nr; si = ni;
        Sr[k] = sr; Si[k] = si;
    }
    float vr = sr, vi = si;
    float W4r = Wr * Wr - Wi * Wi, W4i = 2.f * Wr * Wi;
    { float nr = W4r * W4r - W4i * W4i, ni = 2.f * W4r * W4i;
      W4r = nr; W4i = ni; }
    float stepR = W4r, stepI = W4i;
#pragma unroll
    for (int d = 1; d < 64; d <<= 1) {
        float tr = __shfl_up(vr, d, 64);
        float ti = __shfl_up(vi, d, 64);
        float nr = stepR * tr - stepI * ti + vr;
        float ni = stepR * ti + stepI * tr + vi;
        if (lane >= d) { vr = nr; vi = ni; }
        float r2 = stepR * stepR - stepI * stepI;
        float i2 = 2.f * stepR * stepI;
        stepR = r2; stepI = i2;
    }
    float txr = __shfl_up(vr, 1, 64);
    float txi = __shfl_up(vi, 1, 64);
    if (lane == 0) { txr = 0.f; txi = 0.f; }
    P[(size_t)(4 * lane) * N_DIM + ch]         = txr;
    P[(size_t)(4 * lane) * N_DIM + H_DIM + ch] = txi;
    float qr = txr, qi = txi;
#pragma unroll
    for (int k = 1; k < 4; k++) {
        float nr = Wr * qr - Wi * qi;
        float ni = Wr * qi + Wi * qr;
        qr = nr; qi = ni;
        P[(size_t)(4 * lane + k) * N_DIM + ch]         = qr + Sr[k - 1];
        P[(size_t)(4 * lane + k) * N_DIM + H_DIM + ch] = qi + Si[k - 1];
    }
}

// ---------------- kernel 4c: final scan with carry-in, NT stores ----------------

template <bool BF16IN>
__global__ void scanC(const void* __restrict__ v, float* __restrict__ out,
                      const float* __restrict__ pa, const float* __restrict__ pb,
                      const float* __restrict__ P) {
    int h4 = (blockIdx.x * 256 + threadIdx.x) * 4;
    int c = blockIdx.y;
    f32x4 a = *(const f32x4*)(pa + h4);
    f32x4 b = *(const f32x4*)(pb + h4);
    f32x4 h1 = *(const f32x4*)(P + (size_t)c * N_DIM + h4);
    f32x4 h2 = *(const f32x4*)(P + (size_t)c * N_DIM + H_DIM + h4);
    const unsigned short* pb16 = (const unsigned short*)v + (size_t)c * CHUNK * N_DIM + h4;
    const float* pf = (const float*)v + (size_t)c * CHUNK * N_DIM + h4;
    float* po = out + (size_t)c * CHUNK * N_DIM + h4;
#pragma unroll 8
    for (int t = 0; t < CHUNK; t++) {
        f32x4 v1, v2;
        if (BF16IN) {
            uint2 u1 = *(const uint2*)(pb16);
            uint2 u2 = *(const uint2*)(pb16 + H_DIM);
            v1 = (f32x4){blo(u1.x), bhi(u1.x), blo(u1.y), bhi(u1.y)};
            v2 = (f32x4){blo(u2.x), bhi(u2.x), blo(u2.y), bhi(u2.y)};
            pb16 += N_DIM;
        } else {
            v1 = *(const f32x4*)(pf);
            v2 = *(const f32x4*)(pf + H_DIM);
            pf += N_DIM;
        }
        CSTEP(a.x, b.x, h1.x, h2.x, v1.x, v2.x);
        CSTEP(a.y, b.y, h1.y, h2.y, v1.y, v2.y);
        CSTEP(a.z, b.z, h1.z, h2.z, v1.z, v2.z);
        CSTEP(a.w, b.w, h1.w, h2.w, v1.w, v2.w);
        __builtin_nontemporal_store(h1, (f32x4*)(po));
        __builtin_nontemporal_store(h2, (f32x4*)(po + H_DIM));
        po += N_DIM;
    }
}

// ---------------- launcher ----------------
// Fused path ws layout (needs 97 MiB):
//   [0,8Mi)    Bi (interleaved bf16 B)    [8Mi,+24Ki) pa,pb,pg
//   [9Mi,25Mi) xb   [25Mi,89Mi) V (bf16 v)   [89Mi,93Mi) E   [93Mi,97Mi) P
// Fallback = R5 proven layout (89.4 MiB) or fp32-in-out path.

extern "C" void kernel_launch(void* const* d_in, const int* in_sizes, int n_in,
                              void* d_out, int out_size, void* d_ws, size_t ws_size,
                              hipStream_t stream) {
    const float* x     = (const float*)d_in[0];
    const float* lamda = (const float*)d_in[1];
    const float* theta = (const float*)d_in[2];
    const float* B1    = (const float*)d_in[3];
    const float* B2    = (const float*)d_in[4];
    float* out = (float*)d_out;

    char* ws = (char*)d_ws;
    const size_t MiB = 1024 * 1024;
    const size_t need_fused = 97 * MiB;
    const size_t need_bf16  = 25 * MiB + (size_t)T_DIM * N_DIM * 2;  // R5 layout

    if (ws_size >= need_fused) {
        unsigned short* Bi = (unsigned short*)ws;                       // 8 MiB
        float* pa = (float*)(ws + 8 * MiB);
        float* pb = pa + H_DIM;
        float* pg = pb + H_DIM;
        unsigned short* xb = (unsigned short*)(ws + 9 * MiB);           // 16 MiB
        unsigned short* V  = (unsigned short*)(ws + 25 * MiB);          // 64 MiB
        float* E = (float*)(ws + 89 * MiB);                             // 4 MiB
        float* P = (float*)(ws + 93 * MiB);                             // 4 MiB

        hipLaunchKernelGGL(params_kernel, dim3(H_DIM / 256), dim3(256), 0, stream,
                           lamda, theta, pa, pb, pg);
        hipLaunchKernelGGL(cvt_x, dim3((T_DIM * D_DIM / 4) / 256), dim3(256), 0, stream,
                           (const float4*)x, (ushort4*)xb, T_DIM * D_DIM / 4);
        hipLaunchKernelGGL(cvt_B, dim3((2 * H_DIM * D_DIM / 4) / 256), dim3(256), 0, stream,
                           (const float4*)B1, (const float4*)B2, (ushort4*)Bi, 1);
        hipLaunchKernelGGL(gemm_fused, dim3(T_DIM / 128, H_DIM / 64), dim3(256), 0, stream,
                           xb, Bi, pg, pa, pb, V, E);
        hipLaunchKernelGGL(scanB_wave, dim3(H_DIM / 4), dim3(256), 0, stream, pa, pb, E, P);
        dim3 sgrid(H_DIM / 4 / 256, NCH);
        scanC<true><<<sgrid, dim3(256), 0, stream>>>(V, out, pa, pb, P);
        return;
    }

    // ---------- fallback paths (R5, proven) ----------
    unsigned short* xb = (unsigned short*)ws;                              // 16 MiB
    float* E  = (float*)ws;                                                // aliases xb
    float* P  = (float*)(ws + 4 * MiB);                                    // aliases xb
    unsigned short* Bb = (unsigned short*)(ws + 16 * MiB);                 // 8 MiB
    float* pa = (float*)(ws + 24 * MiB);
    float* pb = pa + H_DIM;
    float* pg = pb + H_DIM;
    unsigned short* vb = (unsigned short*)(ws + 25 * MiB);                 // 64 MiB
    const bool use_bf16 = (ws_size >= need_bf16);

    hipLaunchKernelGGL(params_kernel, dim3(H_DIM / 256), dim3(256), 0, stream,
                       lamda, theta, pa, pb, pg);
    hipLaunchKernelGGL(cvt_x, dim3((T_DIM * D_DIM / 4) / 256), dim3(256), 0, stream,
                       (const float4*)x, (ushort4*)xb, T_DIM * D_DIM / 4);
    hipLaunchKernelGGL(cvt_B, dim3((2 * H_DIM * D_DIM / 4) / 256), dim3(256), 0, stream,
                       (const float4*)B1, (const float4*)B2, (ushort4*)Bb, 0);

    dim3 sgrid(H_DIM / 4 / 256, NCH);
    if (use_bf16) {
        gemm_bt<true><<<dim3(T_DIM / 128, N_DIM / 128), dim3(256), 0, stream>>>(xb, Bb, pg, (void*)vb);
        scanA<true><<<sgrid, dim3(256), 0, stream>>>(vb, pa, pb, E);
        hipLaunchKernelGGL(scanB_wave, dim3(H_DIM / 4), dim3(256), 0, stream, pa, pb, E, P);
        scanC<true><<<sgrid, dim3(256), 0, stream>>>(vb, out, pa, pb, P);
    } else {
        gemm_bt<false><<<dim3(T_DIM / 128, N_DIM / 128), dim3(256), 0, stream>>>(xb, Bb, pg, (void*)out);
        scanA<false><<<sgrid, dim3(256), 0, stream>>>(out, pa, pb, E);
        hipLaunchKernelGGL(scanB_wave, dim3(H_DIM / 4), dim3(256), 0, stream, pa, pb, E, P);
        scanC<false><<<sgrid, dim3(256), 0, stream>>>(out, out, pa, pb, P);
    }
}